// Round 1
// baseline (198.315 us; speedup 1.0000x reference)
//
#include <hip/hip_runtime.h>
#include <hip/hip_bf16.h>

#define BATCH 16
#define NNODE 2000
#define HDIM  128
#define KNN   5
#define NROWS (BATCH * NNODE)   // 32000

// ---------------------------------------------------------------------------
// Kernel 1: per-row top-5 smallest distances + softmax over -dist.
// One wave (64 lanes) per row; 4 waves per 256-thread block.
// ---------------------------------------------------------------------------
__device__ __forceinline__ unsigned long long pack_di(float v, unsigned int idx) {
    unsigned int b = __float_as_uint(v);
    // order-preserving map: float compare == unsigned compare
    b = (b & 0x80000000u) ? ~b : (b | 0x80000000u);
    return ((unsigned long long)b << 32) | idx;
}

__global__ __launch_bounds__(256) void knn_softmax_kernel(
    const float* __restrict__ dist,
    int* __restrict__ w_idx,
    float* __restrict__ w_val)
{
    int row  = blockIdx.x * 4 + (threadIdx.x >> 6);
    int lane = threadIdx.x & 63;
    const float4* r4 = reinterpret_cast<const float4*>(dist + (size_t)row * NNODE);

    // per-lane sorted top-5 (ascending packed keys)
    unsigned long long pk0 = ~0ull, pk1 = ~0ull, pk2 = ~0ull, pk3 = ~0ull, pk4 = ~0ull;

    auto ins = [&](float d, int m) {
        unsigned long long key = pack_di(d, (unsigned int)m);
        if (key < pk4) {
            pk4 = key;
            unsigned long long t;
            if (pk4 < pk3) { t = pk3; pk3 = pk4; pk4 = t; }
            if (pk3 < pk2) { t = pk2; pk2 = pk3; pk3 = t; }
            if (pk2 < pk1) { t = pk1; pk1 = pk2; pk2 = t; }
            if (pk1 < pk0) { t = pk0; pk0 = pk1; pk1 = t; }
        }
    };

    for (int t = lane; t < NNODE / 4; t += 64) {
        float4 v = r4[t];
        int base = t * 4;
        ins(v.x, base); ins(v.y, base + 1); ins(v.z, base + 2); ins(v.w, base + 3);
    }

    // merge across the wave: 5 rounds of butterfly-min; winner lane pops.
    unsigned long long chosen[KNN];
    #pragma unroll
    for (int r = 0; r < KNN; ++r) {
        unsigned long long mn = pk0;
        #pragma unroll
        for (int off = 32; off; off >>= 1) {
            unsigned long long o = __shfl_xor(mn, off, 64);
            if (o < mn) mn = o;
        }
        if (pk0 == mn) { pk0 = pk1; pk1 = pk2; pk2 = pk3; pk3 = pk4; pk4 = ~0ull; }
        chosen[r] = mn;
    }

    if (lane == 0) {
        float d[KNN]; int ix[KNN];
        #pragma unroll
        for (int r = 0; r < KNN; ++r) {
            unsigned int ub = (unsigned int)(chosen[r] >> 32);
            ub = (ub & 0x80000000u) ? (ub ^ 0x80000000u) : ~ub;
            d[r]  = __uint_as_float(ub);
            ix[r] = (int)(chosen[r] & 0xffffffffu);
        }
        // softmax over scores s_r = -d_r ; max score = -d[0] (d sorted ascending)
        float e[KNN]; float sum = 0.f;
        #pragma unroll
        for (int r = 0; r < KNN; ++r) { e[r] = expf(d[0] - d[r]); sum += e[r]; }
        float inv = 1.f / sum;
        #pragma unroll
        for (int r = 0; r < KNN; ++r) {
            w_idx[row * KNN + r] = ix[r];
            w_val[row * KNN + r] = e[r] * inv;
        }
    }
}

// ---------------------------------------------------------------------------
// Kernel 2: transpose Ws (3 x 128 x 128) -> WT so WT[l][i][j] = W[l][j][i].
// Makes the per-feature matmul read coalesced across lanes.
// ---------------------------------------------------------------------------
__global__ __launch_bounds__(256) void transpose_w_kernel(
    const float* __restrict__ W, float* __restrict__ WT)
{
    int t = blockIdx.x * 256 + threadIdx.x;   // over 3*128*128 = 49152
    if (t < 3 * HDIM * HDIM) {
        int l = t >> 14;          // /16384
        int r = t & 16383;
        int i = r >> 7;
        int j = r & 127;
        WT[t] = W[(l << 14) + (j << 7) + i];
    }
}

// ---------------------------------------------------------------------------
// Kernel 3: one GCN layer: agg = sparse(w) @ h ; delta = relu(agg@W^T + b);
// h_out = LN(h + delta)*gamma + beta.
// 256 threads = 2 groups x 128 threads; each group owns 16 consecutive nodes.
// ---------------------------------------------------------------------------
__global__ __launch_bounds__(256) void layer_kernel(
    const float* __restrict__ h_in,
    const int*   __restrict__ w_idx,
    const float* __restrict__ w_val,
    const float* __restrict__ WT,     // [128][128], WT[i*128+j] = W[j][i]
    const float* __restrict__ bias,
    const float* __restrict__ gamma,
    const float* __restrict__ beta,
    float* __restrict__ h_out)
{
    __shared__ float agg[2][16][HDIM];      // 16 KB
    __shared__ int   sidx[2][16][KNN];
    __shared__ float sw[2][16][KNN];
    __shared__ float wred[2][2][16][2];     // [group][wave][node][sum,sumsq]

    int tid  = threadIdx.x;
    int g    = tid >> 7;        // group 0/1
    int j    = tid & 127;       // feature index
    int lane = tid & 63;
    int wv   = (tid >> 6) & 1;  // wave within group

    int gid   = blockIdx.x * 2 + g;
    int node0 = gid * 16;                 // 16 | 2000 per batch -> no b crossing
    int b     = node0 / NNODE;
    size_t hbase = (size_t)b * NNODE * HDIM;

    if (j < 16 * KNN) {
        int m = j / KNN, k = j % KNN;
        int node = node0 + m;
        sidx[g][m][k] = w_idx[node * KNN + k];
        sw[g][m][k]   = w_val[node * KNN + k];
    }
    __syncthreads();

    // aggregation: agg[m][j] = sum_k w[m][k] * h[b, idx[m][k], j]
    #pragma unroll 4
    for (int m = 0; m < 16; ++m) {
        float a = 0.f;
        #pragma unroll
        for (int k = 0; k < KNN; ++k) {
            a = fmaf(sw[g][m][k], h_in[hbase + (size_t)sidx[g][m][k] * HDIM + j], a);
        }
        agg[g][m][j] = a;
    }
    __syncthreads();

    // matmul: acc[m] = sum_i WT[i*128+j] * agg[m][i]
    float acc[16];
    #pragma unroll
    for (int m = 0; m < 16; ++m) acc[m] = 0.f;
    #pragma unroll 4
    for (int i = 0; i < HDIM; ++i) {
        float w = WT[i * HDIM + j];
        #pragma unroll
        for (int m = 0; m < 16; ++m) acc[m] = fmaf(w, agg[g][m][i], acc[m]);
    }

    float bj  = bias[j];
    float gj  = gamma[j];
    float btj = beta[j];

    // y = h + relu(acc + b); keep y in acc[]
    #pragma unroll
    for (int m = 0; m < 16; ++m) {
        float y = h_in[(size_t)(node0 + m) * HDIM + j] + fmaxf(acc[m] + bj, 0.f);
        acc[m] = y;
    }

    // LayerNorm over 128 features (2 waves per group): butterfly + LDS combine
    #pragma unroll
    for (int m = 0; m < 16; ++m) {
        float s = acc[m], s2 = acc[m] * acc[m];
        #pragma unroll
        for (int off = 32; off; off >>= 1) {
            s  += __shfl_xor(s,  off, 64);
            s2 += __shfl_xor(s2, off, 64);
        }
        if (lane == 0) { wred[g][wv][m][0] = s; wred[g][wv][m][1] = s2; }
    }
    __syncthreads();

    #pragma unroll
    for (int m = 0; m < 16; ++m) {
        float s  = wred[g][0][m][0] + wred[g][1][m][0];
        float s2 = wred[g][0][m][1] + wred[g][1][m][1];
        float mu  = s * (1.f / 128.f);
        float var = s2 * (1.f / 128.f) - mu * mu;
        float rs  = rsqrtf(var + 1e-5f);
        h_out[(size_t)(node0 + m) * HDIM + j] = (acc[m] - mu) * rs * gj + btj;
    }
}

// ---------------------------------------------------------------------------
extern "C" void kernel_launch(void* const* d_in, const int* in_sizes, int n_in,
                              void* d_out, int out_size, void* d_ws, size_t ws_size,
                              hipStream_t stream) {
    const float* node_emb = (const float*)d_in[0];
    const float* dist     = (const float*)d_in[1];
    const float* Ws       = (const float*)d_in[2];
    const float* bs       = (const float*)d_in[3];
    const float* gammas   = (const float*)d_in[4];
    const float* betas    = (const float*)d_in[5];
    float* out = (float*)d_out;

    char* ws = (char*)d_ws;
    int*   w_idx = (int*)  (ws + 0);                       // 32000*5*4   = 640000 B
    float* w_val = (float*)(ws + 640000);                  // 640000 B
    float* WT    = (float*)(ws + 1280000);                 // 3*65536     = 196608 B
    float* h_mid = (float*)(ws + 1476608);                 // 16384000 B

    // 1) kNN + softmax weights
    knn_softmax_kernel<<<NROWS / 4, 256, 0, stream>>>(dist, w_idx, w_val);

    // 2) transpose the three weight matrices
    transpose_w_kernel<<<(3 * HDIM * HDIM + 255) / 256, 256, 0, stream>>>(Ws, WT);

    // 3) three layers: node_emb -> out -> h_mid -> out
    const int nblocks = NROWS / 32;   // 2 groups of 16 nodes per block
    layer_kernel<<<nblocks, 256, 0, stream>>>(node_emb, w_idx, w_val,
        WT,               bs,           gammas,           betas,           out);
    layer_kernel<<<nblocks, 256, 0, stream>>>(out,      w_idx, w_val,
        WT + 16384,       bs + HDIM,    gammas + HDIM,    betas + HDIM,    h_mid);
    layer_kernel<<<nblocks, 256, 0, stream>>>(h_mid,    w_idx, w_val,
        WT + 32768,       bs + 2*HDIM,  gammas + 2*HDIM,  betas + 2*HDIM,  out);
}

// Round 3
// 157.009 us; speedup vs baseline: 1.2631x; 1.2631x over previous
//
#include <hip/hip_runtime.h>
#include <hip/hip_bf16.h>

#define BATCH 16
#define NNODE 2000
#define HDIM  128
#define KNN   5
#define NROWS (BATCH * NNODE)   // 32000
#define LN_EPS 1e-5f

typedef __attribute__((ext_vector_type(8))) short short8;
typedef __attribute__((ext_vector_type(4))) float f32x4;

// ---------------------------------------------------------------------------
// Kernel 1: per-row top-5 smallest distances + softmax over -dist.
// One wave (64 lanes) per row; 4 waves per 256-thread block. HBM-bound floor.
// ---------------------------------------------------------------------------
__device__ __forceinline__ unsigned long long pack_di(float v, unsigned int idx) {
    unsigned int b = __float_as_uint(v);
    b = (b & 0x80000000u) ? ~b : (b | 0x80000000u);   // order-preserving
    return ((unsigned long long)b << 32) | idx;
}

__global__ __launch_bounds__(256) void knn_softmax_kernel(
    const float* __restrict__ dist,
    int* __restrict__ w_idx,
    float* __restrict__ w_val)
{
    int row  = blockIdx.x * 4 + (threadIdx.x >> 6);
    int lane = threadIdx.x & 63;
    const float4* r4 = reinterpret_cast<const float4*>(dist + (size_t)row * NNODE);

    unsigned long long pk0 = ~0ull, pk1 = ~0ull, pk2 = ~0ull, pk3 = ~0ull, pk4 = ~0ull;

    auto ins = [&](float d, int m) {
        unsigned long long key = pack_di(d, (unsigned int)m);
        if (key < pk4) {
            pk4 = key;
            unsigned long long t;
            if (pk4 < pk3) { t = pk3; pk3 = pk4; pk4 = t; }
            if (pk3 < pk2) { t = pk2; pk2 = pk3; pk3 = t; }
            if (pk2 < pk1) { t = pk1; pk1 = pk2; pk2 = t; }
            if (pk1 < pk0) { t = pk0; pk0 = pk1; pk1 = t; }
        }
    };

    for (int t = lane; t < NNODE / 4; t += 64) {
        float4 v = r4[t];
        int base = t * 4;
        ins(v.x, base); ins(v.y, base + 1); ins(v.z, base + 2); ins(v.w, base + 3);
    }

    unsigned long long chosen[KNN];
    #pragma unroll
    for (int r = 0; r < KNN; ++r) {
        unsigned long long mn = pk0;
        #pragma unroll
        for (int off = 32; off; off >>= 1) {
            unsigned long long o = __shfl_xor(mn, off, 64);
            if (o < mn) mn = o;
        }
        if (pk0 == mn) { pk0 = pk1; pk1 = pk2; pk2 = pk3; pk3 = pk4; pk4 = ~0ull; }
        chosen[r] = mn;
    }

    if (lane == 0) {
        float d[KNN]; int ix[KNN];
        #pragma unroll
        for (int r = 0; r < KNN; ++r) {
            unsigned int ub = (unsigned int)(chosen[r] >> 32);
            ub = (ub & 0x80000000u) ? (ub ^ 0x80000000u) : ~ub;
            d[r]  = __uint_as_float(ub);
            ix[r] = (int)(chosen[r] & 0xffffffffu);
        }
        float e[KNN]; float sum = 0.f;
        #pragma unroll
        for (int r = 0; r < KNN; ++r) { e[r] = expf(d[0] - d[r]); sum += e[r]; }
        float inv = 1.f / sum;
        #pragma unroll
        for (int r = 0; r < KNN; ++r) {
            w_idx[row * KNN + r] = ix[r];
            w_val[row * KNN + r] = e[r] * inv;
        }
    }
}

// ---------------------------------------------------------------------------
// Kernel 2: one GCN layer via MFMA.
// Block = 256 threads = 4 waves, owns 16 consecutive nodes (one batch).
//  - aggregation (fp32 gathers) -> bf16 agg[16][128] in LDS
//  - each wave: C(16x32) = agg(16x128) @ W^T(128x32) with 8 mfma_16x16x32_bf16
//    (B-fragments converted from fp32 W rows directly: contiguous 32B loads)
//  - epilogue on fragments: y = h + relu(C + b); LN via 16-lane shuffles +
//    cross-wave LDS combine.
// MFMA layouts (gfx950, verified): A row=l%16, k=(l/16)*8+e; B col=l%16,
// k=(l/16)*8+e; C/D col=l&15, row=(l>>4)*4+reg.
// ---------------------------------------------------------------------------
__global__ __launch_bounds__(256) void layer_kernel(
    const float* __restrict__ h_in,
    const int*   __restrict__ w_idx,
    const float* __restrict__ w_val,
    const float* __restrict__ Wfp,    // [128][128] fp32, W[j][k] (row = out col)
    const float* __restrict__ bias,
    const float* __restrict__ gamma,
    const float* __restrict__ beta,
    float* __restrict__ h_out)
{
    __shared__ __hip_bfloat16 aggb[16][HDIM];   // 4 KB
    __shared__ int   sidx[16][KNN];
    __shared__ float sw[16][KNN];
    __shared__ float wred[4][16][2];            // [wave][row][sum,sumsq]

    int tid = threadIdx.x;
    int wv  = tid >> 6;        // wave 0..3
    int l   = tid & 63;        // lane
    int node0 = blockIdx.x * 16;               // 16 | 2000 -> no batch crossing
    int b     = node0 / NNODE;
    size_t hbase = (size_t)b * NNODE * HDIM;

    // ---- B fragments: lane needs W[col][ks*32 + (l>>4)*8 + 0..7], fp32->bf16
    short8 bfrag[2][4];
    #pragma unroll
    for (int ct = 0; ct < 2; ++ct) {
        int col = wv * 32 + ct * 16 + (l & 15);
        const float4* wp = reinterpret_cast<const float4*>(Wfp) + col * 32 + (l >> 4) * 2;
        #pragma unroll
        for (int ks = 0; ks < 4; ++ks) {
            float4 u0 = wp[ks * 8];
            float4 u1 = wp[ks * 8 + 1];
            float vv[8] = {u0.x,u0.y,u0.z,u0.w,u1.x,u1.y,u1.z,u1.w};
            short8 r;
            #pragma unroll
            for (int e = 0; e < 8; ++e) {
                __hip_bfloat16 hb = __float2bfloat16(vv[e]);
                r[e] = *reinterpret_cast<short*>(&hb);
            }
            bfrag[ct][ks] = r;
        }
    }

    if (tid < 16 * KNN) {
        int m = tid / KNN, k = tid % KNN;
        sidx[m][k] = w_idx[(node0 + m) * KNN + k];
        sw[m][k]   = w_val[(node0 + m) * KNN + k];
    }
    __syncthreads();

    // ---- aggregation: thread t -> node m = t>>4, cols c0 = (t&15)*8
    {
        int m  = tid >> 4;
        int c0 = (tid & 15) * 8;
        float a0=0,a1=0,a2=0,a3=0,a4=0,a5=0,a6=0,a7=0;
        #pragma unroll
        for (int k = 0; k < KNN; ++k) {
            float wk = sw[m][k];
            const float4* p = reinterpret_cast<const float4*>(
                h_in + hbase + (size_t)sidx[m][k] * HDIM + c0);
            float4 v0 = p[0], v1 = p[1];
            a0 = fmaf(wk, v0.x, a0); a1 = fmaf(wk, v0.y, a1);
            a2 = fmaf(wk, v0.z, a2); a3 = fmaf(wk, v0.w, a3);
            a4 = fmaf(wk, v1.x, a4); a5 = fmaf(wk, v1.y, a5);
            a6 = fmaf(wk, v1.z, a6); a7 = fmaf(wk, v1.w, a7);
        }
        float vv[8] = {a0,a1,a2,a3,a4,a5,a6,a7};
        short8 pk;
        #pragma unroll
        for (int e = 0; e < 8; ++e) {
            __hip_bfloat16 hb = __float2bfloat16(vv[e]);
            pk[e] = *reinterpret_cast<short*>(&hb);
        }
        *reinterpret_cast<short8*>(&aggb[m][c0]) = pk;
    }
    __syncthreads();

    // ---- MFMA: per wave, C(16x32) over 4 k-steps
    f32x4 acc0 = {0.f,0.f,0.f,0.f}, acc1 = {0.f,0.f,0.f,0.f};
    #pragma unroll
    for (int ks = 0; ks < 4; ++ks) {
        short8 afrag = *reinterpret_cast<const short8*>(&aggb[l & 15][ks * 32 + (l >> 4) * 8]);
        acc0 = __builtin_amdgcn_mfma_f32_16x16x32_bf16(afrag, bfrag[0][ks], acc0, 0, 0, 0);
        acc1 = __builtin_amdgcn_mfma_f32_16x16x32_bf16(afrag, bfrag[1][ks], acc1, 0, 0, 0);
    }

    // ---- epilogue: y = h + relu(C + bias)
    int g = l >> 4;                 // rows g*4 .. g*4+3
    int col0 = wv * 32 + (l & 15);
    int col1 = col0 + 16;
    float b0  = bias[col0],  b1  = bias[col1];
    float gm0 = gamma[col0], gm1 = gamma[col1];
    float bt0 = beta[col0],  bt1 = beta[col1];

    float y0[4], y1[4];
    #pragma unroll
    for (int r = 0; r < 4; ++r) {
        int row = node0 + g * 4 + r;
        float h0 = h_in[(size_t)row * HDIM + col0];
        float h1 = h_in[(size_t)row * HDIM + col1];
        y0[r] = h0 + fmaxf(acc0[r] + b0, 0.f);
        y1[r] = h1 + fmaxf(acc1[r] + b1, 0.f);
    }

    // per-wave row stats over this wave's 32 cols (reduce across 16 lanes)
    #pragma unroll
    for (int r = 0; r < 4; ++r) {
        float ss = y0[r] + y1[r];
        float qq = y0[r] * y0[r] + y1[r] * y1[r];
        #pragma unroll
        for (int off = 1; off < 16; off <<= 1) {
            ss += __shfl_xor(ss, off, 64);
            qq += __shfl_xor(qq, off, 64);
        }
        if ((l & 15) == 0) { wred[wv][g * 4 + r][0] = ss; wred[wv][g * 4 + r][1] = qq; }
    }
    __syncthreads();

    #pragma unroll
    for (int r = 0; r < 4; ++r) {
        int row = g * 4 + r;
        float S = wred[0][row][0] + wred[1][row][0] + wred[2][row][0] + wred[3][row][0];
        float Q = wred[0][row][1] + wred[1][row][1] + wred[2][row][1] + wred[3][row][1];
        float mu  = S * (1.f / 128.f);
        float var = Q * (1.f / 128.f) - mu * mu;
        float rs  = rsqrtf(var + LN_EPS);
        size_t orow = (size_t)(node0 + row) * HDIM;
        h_out[orow + col0] = (y0[r] - mu) * rs * gm0 + bt0;
        h_out[orow + col1] = (y1[r] - mu) * rs * gm1 + bt1;
    }
}

// ---------------------------------------------------------------------------
extern "C" void kernel_launch(void* const* d_in, const int* in_sizes, int n_in,
                              void* d_out, int out_size, void* d_ws, size_t ws_size,
                              hipStream_t stream) {
    const float* node_emb = (const float*)d_in[0];
    const float* dist     = (const float*)d_in[1];
    const float* Ws       = (const float*)d_in[2];
    const float* bs       = (const float*)d_in[3];
    const float* gammas   = (const float*)d_in[4];
    const float* betas    = (const float*)d_in[5];
    float* out = (float*)d_out;

    char* ws = (char*)d_ws;
    int*   w_idx = (int*)  (ws + 0);            // 32000*5*4 = 640000 B
    float* w_val = (float*)(ws + 640000);       // 640000 B
    float* h_mid = (float*)(ws + 1280000);      // 16384000 B

    knn_softmax_kernel<<<NROWS / 4, 256, 0, stream>>>(dist, w_idx, w_val);

    const int nblocks = NROWS / 16;   // 2000
    layer_kernel<<<nblocks, 256, 0, stream>>>(node_emb, w_idx, w_val,
        Ws,               bs,            gammas,            betas,            out);
    layer_kernel<<<nblocks, 256, 0, stream>>>(out,      w_idx, w_val,
        Ws + 16384,       bs + HDIM,     gammas + HDIM,     betas + HDIM,     h_mid);
    layer_kernel<<<nblocks, 256, 0, stream>>>(h_mid,    w_idx, w_val,
        Ws + 32768,       bs + 2*HDIM,   gammas + 2*HDIM,   betas + 2*HDIM,   out);
}

// Round 5
// 118.071 us; speedup vs baseline: 1.6796x; 1.3298x over previous
//
#include <hip/hip_runtime.h>
#include <hip/hip_bf16.h>

#define BATCH 16
#define NNODE 2000
#define HDIM  128
#define KNN   5
#define NROWS (BATCH * NNODE)   // 32000
#define LN_EPS 1e-5f

typedef __attribute__((ext_vector_type(8))) short short8;
typedef __attribute__((ext_vector_type(4))) float f32x4;

// ---------------------------------------------------------------------------
// Kernel 0: pre-convert Ws (3 x 128 x 128 fp32) into bf16 laid out in MFMA
// B-fragment order: entry f = (((wv*2+ct)*4+ks)*64+lane) of layer l holds
// W[l][col][k0..k0+7] with col = wv*32+ct*16+(lane&15), k0 = ks*32+(lane>>4)*8.
// Layer kernels then load fragments as fully-coalesced short8 reads.
// ---------------------------------------------------------------------------
__global__ __launch_bounds__(256) void prep_w_kernel(
    const float* __restrict__ Ws, __hip_bfloat16* __restrict__ WB)
{
    int t = blockIdx.x * 256 + threadIdx.x;     // 3*2048 short8 entries
    if (t >= 3 * 2048) return;
    int l    = t >> 11;
    int r    = t & 2047;
    int lane = r & 63;
    int ks   = (r >> 6) & 3;
    int ct   = (r >> 8) & 1;
    int wv   = (r >> 9) & 3;
    int col  = wv * 32 + ct * 16 + (lane & 15);
    int k0   = ks * 32 + (lane >> 4) * 8;
    const float* src = Ws + ((size_t)l << 14) + col * HDIM + k0;
    __hip_bfloat16* dst = WB + ((size_t)t << 3);
    #pragma unroll
    for (int e = 0; e < 8; ++e) dst[e] = __float2bfloat16(src[e]);
}

// ---------------------------------------------------------------------------
// Kernel 1: per-row top-5 smallest distances + softmax over -dist.
// One wave per row; all 8 row-slice float4 loads issued up front (8-deep MLP)
// so the wave is HBM-BW-bound, not latency-serialized.
// ---------------------------------------------------------------------------
__device__ __forceinline__ unsigned long long pack_di(float v, unsigned int idx) {
    unsigned int b = __float_as_uint(v);
    b = (b & 0x80000000u) ? ~b : (b | 0x80000000u);   // order-preserving
    return ((unsigned long long)b << 32) | idx;
}

__global__ __launch_bounds__(256) void knn_softmax_kernel(
    const float* __restrict__ dist,
    int* __restrict__ w_idx,
    float* __restrict__ w_val)
{
    int row  = blockIdx.x * 4 + (threadIdx.x >> 6);
    int lane = threadIdx.x & 63;
    const float4* r4 = reinterpret_cast<const float4*>(dist + (size_t)row * NNODE);

    unsigned long long pk0 = ~0ull, pk1 = ~0ull, pk2 = ~0ull, pk3 = ~0ull, pk4 = ~0ull;

    auto ins = [&](float d, int m) {
        unsigned long long key = pack_di(d, (unsigned int)m);
        if (key < pk4) {
            pk4 = key;
            unsigned long long t;
            if (pk4 < pk3) { t = pk3; pk3 = pk4; pk4 = t; }
            if (pk3 < pk2) { t = pk2; pk2 = pk3; pk3 = t; }
            if (pk2 < pk1) { t = pk1; pk1 = pk2; pk2 = t; }
            if (pk1 < pk0) { t = pk0; pk0 = pk1; pk1 = t; }
        }
    };

    // 500 float4s per row: lanes 0..51 handle 8, lanes 52..63 handle 7.
    float4 v[8];
    int base7 = lane + 448;
    bool has8 = base7 < (NNODE / 4);
    #pragma unroll
    for (int i = 0; i < 7; ++i) v[i] = r4[lane + 64 * i];
    v[7] = r4[has8 ? base7 : lane];     // in-row safe address

    #pragma unroll
    for (int i = 0; i < 7; ++i) {
        int base = (lane + 64 * i) * 4;
        ins(v[i].x, base); ins(v[i].y, base + 1);
        ins(v[i].z, base + 2); ins(v[i].w, base + 3);
    }
    if (has8) {
        int base = base7 * 4;
        ins(v[7].x, base); ins(v[7].y, base + 1);
        ins(v[7].z, base + 2); ins(v[7].w, base + 3);
    }

    unsigned long long chosen[KNN];
    #pragma unroll
    for (int r = 0; r < KNN; ++r) {
        unsigned long long mn = pk0;
        #pragma unroll
        for (int off = 32; off; off >>= 1) {
            unsigned long long o = __shfl_xor(mn, off, 64);
            if (o < mn) mn = o;
        }
        if (pk0 == mn) { pk0 = pk1; pk1 = pk2; pk2 = pk3; pk3 = pk4; pk4 = ~0ull; }
        chosen[r] = mn;
    }

    if (lane == 0) {
        float d[KNN]; int ix[KNN];
        #pragma unroll
        for (int r = 0; r < KNN; ++r) {
            unsigned int ub = (unsigned int)(chosen[r] >> 32);
            ub = (ub & 0x80000000u) ? (ub ^ 0x80000000u) : ~ub;
            d[r]  = __uint_as_float(ub);
            ix[r] = (int)(chosen[r] & 0xffffffffu);
        }
        float e[KNN]; float sum = 0.f;
        #pragma unroll
        for (int r = 0; r < KNN; ++r) { e[r] = expf(d[0] - d[r]); sum += e[r]; }
        float inv = 1.f / sum;
        #pragma unroll
        for (int r = 0; r < KNN; ++r) {
            w_idx[row * KNN + r] = ix[r];
            w_val[row * KNN + r] = e[r] * inv;
        }
    }
}

// ---------------------------------------------------------------------------
// Kernel 2: one GCN layer via MFMA.
// Block = 4 waves, 16 consecutive nodes. agg (fp32 gathers) -> bf16 LDS;
// each wave C(16x32) = agg(16x128) @ W^T(128x32) with 8 mfma_16x16x32_bf16;
// B-fragments are 8 coalesced short8 loads from the pre-packed WB.
// MFMA layouts (gfx950, verified): A row=l%16, k=(l/16)*8+e; B col=l%16,
// same k; C/D col=l&15, row=(l>>4)*4+reg.
// ---------------------------------------------------------------------------
__global__ __launch_bounds__(256) void layer_kernel(
    const float* __restrict__ h_in,
    const int*   __restrict__ w_idx,
    const float* __restrict__ w_val,
    const __hip_bfloat16* __restrict__ WB,   // fragment-ordered, this layer
    const float* __restrict__ bias,
    const float* __restrict__ gamma,
    const float* __restrict__ beta,
    float* __restrict__ h_out)
{
    __shared__ __hip_bfloat16 aggb[16][HDIM];   // 4 KB
    __shared__ int   sidx[16][KNN];
    __shared__ float sw[16][KNN];
    __shared__ float wred[4][16][2];            // [wave][row][sum,sumsq]

    int tid = threadIdx.x;
    int wv  = tid >> 6;
    int l   = tid & 63;
    int node0 = blockIdx.x * 16;               // 16 | 2000 -> no batch crossing
    int b     = node0 / NNODE;
    size_t hbase = (size_t)b * NNODE * HDIM;

    // ---- B fragments: 8 coalesced short8 loads (1 KB per wave-instr)
    const short8* wb = reinterpret_cast<const short8*>(WB);
    short8 bfrag[2][4];
    #pragma unroll
    for (int ct = 0; ct < 2; ++ct)
        #pragma unroll
        for (int ks = 0; ks < 4; ++ks)
            bfrag[ct][ks] = wb[((wv * 2 + ct) * 4 + ks) * 64 + l];

    if (tid < 16 * KNN) {
        int m = tid / KNN, k = tid % KNN;
        sidx[m][k] = w_idx[(node0 + m) * KNN + k];
        sw[m][k]   = w_val[(node0 + m) * KNN + k];
    }
    __syncthreads();

    // ---- aggregation: thread t -> node m = t>>4, cols c0 = (t&15)*8
    {
        int m  = tid >> 4;
        int c0 = (tid & 15) * 8;
        float a0=0,a1=0,a2=0,a3=0,a4=0,a5=0,a6=0,a7=0;
        #pragma unroll
        for (int k = 0; k < KNN; ++k) {
            float wk = sw[m][k];
            const float4* p = reinterpret_cast<const float4*>(
                h_in + hbase + (size_t)sidx[m][k] * HDIM + c0);
            float4 v0 = p[0], v1 = p[1];
            a0 = fmaf(wk, v0.x, a0); a1 = fmaf(wk, v0.y, a1);
            a2 = fmaf(wk, v0.z, a2); a3 = fmaf(wk, v0.w, a3);
            a4 = fmaf(wk, v1.x, a4); a5 = fmaf(wk, v1.y, a5);
            a6 = fmaf(wk, v1.z, a6); a7 = fmaf(wk, v1.w, a7);
        }
        float vv[8] = {a0,a1,a2,a3,a4,a5,a6,a7};
        short8 pk;
        #pragma unroll
        for (int e = 0; e < 8; ++e) {
            __hip_bfloat16 hb = __float2bfloat16(vv[e]);
            pk[e] = *reinterpret_cast<short*>(&hb);
        }
        *reinterpret_cast<short8*>(&aggb[m][c0]) = pk;
    }
    __syncthreads();

    // ---- MFMA: per wave, C(16x32) over 4 k-steps
    f32x4 acc0 = {0.f,0.f,0.f,0.f}, acc1 = {0.f,0.f,0.f,0.f};
    #pragma unroll
    for (int ks = 0; ks < 4; ++ks) {
        short8 afrag = *reinterpret_cast<const short8*>(&aggb[l & 15][ks * 32 + (l >> 4) * 8]);
        acc0 = __builtin_amdgcn_mfma_f32_16x16x32_bf16(afrag, bfrag[0][ks], acc0, 0, 0, 0);
        acc1 = __builtin_amdgcn_mfma_f32_16x16x32_bf16(afrag, bfrag[1][ks], acc1, 0, 0, 0);
    }

    // ---- epilogue: y = h + relu(C + bias)
    int g = l >> 4;
    int col0 = wv * 32 + (l & 15);
    int col1 = col0 + 16;
    float b0  = bias[col0],  b1  = bias[col1];
    float gm0 = gamma[col0], gm1 = gamma[col1];
    float bt0 = beta[col0],  bt1 = beta[col1];

    float y0[4], y1[4];
    #pragma unroll
    for (int r = 0; r < 4; ++r) {
        int row = node0 + g * 4 + r;
        float h0 = h_in[(size_t)row * HDIM + col0];
        float h1 = h_in[(size_t)row * HDIM + col1];
        y0[r] = h0 + fmaxf(acc0[r] + b0, 0.f);
        y1[r] = h1 + fmaxf(acc1[r] + b1, 0.f);
    }

    #pragma unroll
    for (int r = 0; r < 4; ++r) {
        float ss = y0[r] + y1[r];
        float qq = y0[r] * y0[r] + y1[r] * y1[r];
        #pragma unroll
        for (int off = 1; off < 16; off <<= 1) {
            ss += __shfl_xor(ss, off, 64);
            qq += __shfl_xor(qq, off, 64);
        }
        if ((l & 15) == 0) { wred[wv][g * 4 + r][0] = ss; wred[wv][g * 4 + r][1] = qq; }
    }
    __syncthreads();

    #pragma unroll
    for (int r = 0; r < 4; ++r) {
        int row = g * 4 + r;
        float S = wred[0][row][0] + wred[1][row][0] + wred[2][row][0] + wred[3][row][0];
        float Q = wred[0][row][1] + wred[1][row][1] + wred[2][row][1] + wred[3][row][1];
        float mu  = S * (1.f / 128.f);
        float var = Q * (1.f / 128.f) - mu * mu;
        float rs  = rsqrtf(var + LN_EPS);
        size_t orow = (size_t)(node0 + row) * HDIM;
        h_out[orow + col0] = (y0[r] - mu) * rs * gm0 + bt0;
        h_out[orow + col1] = (y1[r] - mu) * rs * gm1 + bt1;
    }
}

// ---------------------------------------------------------------------------
extern "C" void kernel_launch(void* const* d_in, const int* in_sizes, int n_in,
                              void* d_out, int out_size, void* d_ws, size_t ws_size,
                              hipStream_t stream) {
    const float* node_emb = (const float*)d_in[0];
    const float* dist     = (const float*)d_in[1];
    const float* Ws       = (const float*)d_in[2];
    const float* bs       = (const float*)d_in[3];
    const float* gammas   = (const float*)d_in[4];
    const float* betas    = (const float*)d_in[5];
    float* out = (float*)d_out;

    char* ws = (char*)d_ws;
    int*   w_idx = (int*)  (ws + 0);                      // 640000 B
    float* w_val = (float*)(ws + 640000);                 // 640000 B
    __hip_bfloat16* WB = (__hip_bfloat16*)(ws + 1280000); // 3*32768 = 98304 B
    float* h_mid = (float*)(ws + 1378304);                // 16384000 B

    prep_w_kernel<<<24, 256, 0, stream>>>(Ws, WB);
    knn_softmax_kernel<<<NROWS / 4, 256, 0, stream>>>(dist, w_idx, w_val);

    const int nblocks = NROWS / 16;   // 2000
    const int WL = 16384;             // bf16 elements per layer in WB
    layer_kernel<<<nblocks, 256, 0, stream>>>(node_emb, w_idx, w_val,
        WB,          bs,           gammas,           betas,           out);
    layer_kernel<<<nblocks, 256, 0, stream>>>(out,      w_idx, w_val,
        WB + WL,     bs + HDIM,    gammas + HDIM,    betas + HDIM,    h_mid);
    layer_kernel<<<nblocks, 256, 0, stream>>>(h_mid,    w_idx, w_val,
        WB + 2*WL,   bs + 2*HDIM,  gammas + 2*HDIM,  betas + 2*HDIM,  out);
}

// Round 7
// 110.314 us; speedup vs baseline: 1.7977x; 1.0703x over previous
//
#include <hip/hip_runtime.h>
#include <hip/hip_bf16.h>

#define BATCH 16
#define NNODE 2000
#define HDIM  128
#define KNN   5
#define NROWS (BATCH * NNODE)   // 32000
#define LN_EPS 1e-5f

typedef __attribute__((ext_vector_type(8))) short short8;
typedef __attribute__((ext_vector_type(4))) float f32x4;

// ---------------------------------------------------------------------------
// Kernel 0: pre-convert Ws (3 x 128 x 128 fp32) into bf16 laid out in MFMA
// B-fragment order: entry f = (((wv*2+ct)*4+ks)*64+lane) of layer l holds
// W[l][col][k0..k0+7] with col = wv*32+ct*16+(lane&15), k0 = ks*32+(lane>>4)*8.
// ---------------------------------------------------------------------------
__global__ __launch_bounds__(256) void prep_w_kernel(
    const float* __restrict__ Ws, __hip_bfloat16* __restrict__ WB)
{
    int t = blockIdx.x * 256 + threadIdx.x;     // 3*2048 short8 entries
    if (t >= 3 * 2048) return;
    int l    = t >> 11;
    int r    = t & 2047;
    int lane = r & 63;
    int ks   = (r >> 6) & 3;
    int ct   = (r >> 8) & 1;
    int wv   = (r >> 9) & 3;
    int col  = wv * 32 + ct * 16 + (lane & 15);
    int k0   = ks * 32 + (lane >> 4) * 8;
    const float* src = Ws + ((size_t)l << 14) + col * HDIM + k0;
    __hip_bfloat16* dst = WB + ((size_t)t << 3);
    #pragma unroll
    for (int e = 0; e < 8; ++e) dst[e] = __float2bfloat16(src[e]);
}

// ---------------------------------------------------------------------------
// Kernel 1: per-row top-5 smallest distances + softmax over -dist.
// One wave per row; all 8 row-slice float4 loads issued up front so the wave
// is HBM-BW-bound, not latency-serialized. At ~38 us this is the HBM floor.
// ---------------------------------------------------------------------------
__device__ __forceinline__ unsigned long long pack_di(float v, unsigned int idx) {
    unsigned int b = __float_as_uint(v);
    b = (b & 0x80000000u) ? ~b : (b | 0x80000000u);   // order-preserving
    return ((unsigned long long)b << 32) | idx;
}

__global__ __launch_bounds__(256) void knn_softmax_kernel(
    const float* __restrict__ dist,
    int* __restrict__ w_idx,
    float* __restrict__ w_val)
{
    int row  = blockIdx.x * 4 + (threadIdx.x >> 6);
    int lane = threadIdx.x & 63;
    const float4* r4 = reinterpret_cast<const float4*>(dist + (size_t)row * NNODE);

    unsigned long long pk0 = ~0ull, pk1 = ~0ull, pk2 = ~0ull, pk3 = ~0ull, pk4 = ~0ull;

    auto ins = [&](float d, int m) {
        unsigned long long key = pack_di(d, (unsigned int)m);
        if (key < pk4) {
            pk4 = key;
            unsigned long long t;
            if (pk4 < pk3) { t = pk3; pk3 = pk4; pk4 = t; }
            if (pk3 < pk2) { t = pk2; pk2 = pk3; pk3 = t; }
            if (pk2 < pk1) { t = pk1; pk1 = pk2; pk2 = t; }
            if (pk1 < pk0) { t = pk0; pk0 = pk1; pk1 = t; }
        }
    };

    // 500 float4s per row: lanes 0..51 handle 8, lanes 52..63 handle 7.
    float4 v[8];
    int base7 = lane + 448;
    bool has8 = base7 < (NNODE / 4);
    #pragma unroll
    for (int i = 0; i < 7; ++i) v[i] = r4[lane + 64 * i];
    v[7] = r4[has8 ? base7 : lane];     // in-row safe address

    #pragma unroll
    for (int i = 0; i < 7; ++i) {
        int base = (lane + 64 * i) * 4;
        ins(v[i].x, base); ins(v[i].y, base + 1);
        ins(v[i].z, base + 2); ins(v[i].w, base + 3);
    }
    if (has8) {
        int base = base7 * 4;
        ins(v[7].x, base); ins(v[7].y, base + 1);
        ins(v[7].z, base + 2); ins(v[7].w, base + 3);
    }

    unsigned long long chosen[KNN];
    #pragma unroll
    for (int r = 0; r < KNN; ++r) {
        unsigned long long mn = pk0;
        #pragma unroll
        for (int off = 32; off; off >>= 1) {
            unsigned long long o = __shfl_xor(mn, off, 64);
            if (o < mn) mn = o;
        }
        if (pk0 == mn) { pk0 = pk1; pk1 = pk2; pk2 = pk3; pk3 = pk4; pk4 = ~0ull; }
        chosen[r] = mn;
    }

    if (lane == 0) {
        float d[KNN]; int ix[KNN];
        #pragma unroll
        for (int r = 0; r < KNN; ++r) {
            unsigned int ub = (unsigned int)(chosen[r] >> 32);
            ub = (ub & 0x80000000u) ? (ub ^ 0x80000000u) : ~ub;
            d[r]  = __uint_as_float(ub);
            ix[r] = (int)(chosen[r] & 0xffffffffu);
        }
        float e[KNN]; float sum = 0.f;
        #pragma unroll
        for (int r = 0; r < KNN; ++r) { e[r] = expf(d[0] - d[r]); sum += e[r]; }
        float inv = 1.f / sum;
        #pragma unroll
        for (int r = 0; r < KNN; ++r) {
            w_idx[row * KNN + r] = ix[r];
            w_val[row * KNN + r] = e[r] * inv;
        }
    }
}

// ---------------------------------------------------------------------------
// Kernel 2: one GCN layer via MFMA.
// Block = 4 waves, 16 consecutive nodes. agg (fp32 gathers) -> bf16 LDS;
// each wave C(16x32) = agg(16x128) @ W^T(128x32) with 8 mfma_16x16x32_bf16.
// XCD-aware bijective block swizzle: all 125 blocks of a batch land on one
// XCD (2 batches/XCD) so neighbor-row gathers hit that XCD's private L2
// instead of re-fetching every batch slab from HBM on all 8 XCDs.
// ---------------------------------------------------------------------------
__global__ __launch_bounds__(256) void layer_kernel(
    const float* __restrict__ h_in,
    const int*   __restrict__ w_idx,
    const float* __restrict__ w_val,
    const __hip_bfloat16* __restrict__ WB,   // fragment-ordered, this layer
    const float* __restrict__ bias,
    const float* __restrict__ gamma,
    const float* __restrict__ beta,
    float* __restrict__ h_out)
{
    __shared__ __hip_bfloat16 aggb[16][HDIM];   // 4 KB
    __shared__ int   sidx[16][KNN];
    __shared__ float sw[16][KNN];
    __shared__ float wred[4][16][2];            // [wave][row][sum,sumsq]

    int tid = threadIdx.x;
    int wv  = tid >> 6;
    int l   = tid & 63;

    // ---- XCD swizzle: 2000 blocks = 8 XCDs x 250; batch bsw = 2 per XCD.
    // Assumes round-robin bid->XCD (bid&7). Bijective: j in 0..249 splits
    // into two batches of 125.
    int bid = blockIdx.x;
    int x   = bid & 7;
    int j   = bid >> 3;
    int hi  = (j >= 125);
    int bsw = 2 * x + hi;
    int gid = bsw * 125 + (j - hi * 125);

    int node0 = gid * 16;                     // 16 | 2000 -> no batch crossing
    size_t hbase = (size_t)bsw * NNODE * HDIM;

    // ---- B fragments: 8 coalesced short8 loads (1 KB per wave-instr)
    const short8* wb = reinterpret_cast<const short8*>(WB);
    short8 bfrag[2][4];
    #pragma unroll
    for (int ct = 0; ct < 2; ++ct)
        #pragma unroll
        for (int ks = 0; ks < 4; ++ks)
            bfrag[ct][ks] = wb[((wv * 2 + ct) * 4 + ks) * 64 + l];

    if (tid < 16 * KNN) {
        int m = tid / KNN, k = tid % KNN;
        sidx[m][k] = w_idx[(node0 + m) * KNN + k];
        sw[m][k]   = w_val[(node0 + m) * KNN + k];
    }
    __syncthreads();

    // ---- aggregation: thread t -> node m = t>>4, cols c0 = (t&15)*8
    {
        int m  = tid >> 4;
        int c0 = (tid & 15) * 8;
        float a0=0,a1=0,a2=0,a3=0,a4=0,a5=0,a6=0,a7=0;
        #pragma unroll
        for (int k = 0; k < KNN; ++k) {
            float wk = sw[m][k];
            const float4* p = reinterpret_cast<const float4*>(
                h_in + hbase + (size_t)sidx[m][k] * HDIM + c0);
            float4 v0 = p[0], v1 = p[1];
            a0 = fmaf(wk, v0.x, a0); a1 = fmaf(wk, v0.y, a1);
            a2 = fmaf(wk, v0.z, a2); a3 = fmaf(wk, v0.w, a3);
            a4 = fmaf(wk, v1.x, a4); a5 = fmaf(wk, v1.y, a5);
            a6 = fmaf(wk, v1.z, a6); a7 = fmaf(wk, v1.w, a7);
        }
        float vv[8] = {a0,a1,a2,a3,a4,a5,a6,a7};
        short8 pk;
        #pragma unroll
        for (int e = 0; e < 8; ++e) {
            __hip_bfloat16 hb = __float2bfloat16(vv[e]);
            pk[e] = *reinterpret_cast<short*>(&hb);
        }
        *reinterpret_cast<short8*>(&aggb[m][c0]) = pk;
    }
    __syncthreads();

    // ---- MFMA: per wave, C(16x32) over 4 k-steps
    f32x4 acc0 = {0.f,0.f,0.f,0.f}, acc1 = {0.f,0.f,0.f,0.f};
    #pragma unroll
    for (int ks = 0; ks < 4; ++ks) {
        short8 afrag = *reinterpret_cast<const short8*>(&aggb[l & 15][ks * 32 + (l >> 4) * 8]);
        acc0 = __builtin_amdgcn_mfma_f32_16x16x32_bf16(afrag, bfrag[0][ks], acc0, 0, 0, 0);
        acc1 = __builtin_amdgcn_mfma_f32_16x16x32_bf16(afrag, bfrag[1][ks], acc1, 0, 0, 0);
    }

    // ---- epilogue: y = h + relu(C + bias)
    int g = l >> 4;
    int col0 = wv * 32 + (l & 15);
    int col1 = col0 + 16;
    float b0  = bias[col0],  b1  = bias[col1];
    float gm0 = gamma[col0], gm1 = gamma[col1];
    float bt0 = beta[col0],  bt1 = beta[col1];

    float y0[4], y1[4];
    #pragma unroll
    for (int r = 0; r < 4; ++r) {
        int row = node0 + g * 4 + r;
        float h0 = h_in[(size_t)row * HDIM + col0];
        float h1 = h_in[(size_t)row * HDIM + col1];
        y0[r] = h0 + fmaxf(acc0[r] + b0, 0.f);
        y1[r] = h1 + fmaxf(acc1[r] + b1, 0.f);
    }

    #pragma unroll
    for (int r = 0; r < 4; ++r) {
        float ss = y0[r] + y1[r];
        float qq = y0[r] * y0[r] + y1[r] * y1[r];
        #pragma unroll
        for (int off = 1; off < 16; off <<= 1) {
            ss += __shfl_xor(ss, off, 64);
            qq += __shfl_xor(qq, off, 64);
        }
        if ((l & 15) == 0) { wred[wv][g * 4 + r][0] = ss; wred[wv][g * 4 + r][1] = qq; }
    }
    __syncthreads();

    #pragma unroll
    for (int r = 0; r < 4; ++r) {
        int row = g * 4 + r;
        float S = wred[0][row][0] + wred[1][row][0] + wred[2][row][0] + wred[3][row][0];
        float Q = wred[0][row][1] + wred[1][row][1] + wred[2][row][1] + wred[3][row][1];
        float mu  = S * (1.f / 128.f);
        float var = Q * (1.f / 128.f) - mu * mu;
        float rs  = rsqrtf(var + LN_EPS);
        size_t orow = (size_t)(node0 + row) * HDIM;
        h_out[orow + col0] = (y0[r] - mu) * rs * gm0 + bt0;
        h_out[orow + col1] = (y1[r] - mu) * rs * gm1 + bt1;
    }
}

// ---------------------------------------------------------------------------
extern "C" void kernel_launch(void* const* d_in, const int* in_sizes, int n_in,
                              void* d_out, int out_size, void* d_ws, size_t ws_size,
                              hipStream_t stream) {
    const float* node_emb = (const float*)d_in[0];
    const float* dist     = (const float*)d_in[1];
    const float* Ws       = (const float*)d_in[2];
    const float* bs       = (const float*)d_in[3];
    const float* gammas   = (const float*)d_in[4];
    const float* betas    = (const float*)d_in[5];
    float* out = (float*)d_out;

    char* ws = (char*)d_ws;
    int*   w_idx = (int*)  (ws + 0);                      // 640000 B
    float* w_val = (float*)(ws + 640000);                 // 640000 B
    __hip_bfloat16* WB = (__hip_bfloat16*)(ws + 1280000); // 3*32768 = 98304 B
    float* h_mid = (float*)(ws + 1378304);                // 16384000 B

    prep_w_kernel<<<24, 256, 0, stream>>>(Ws, WB);
    knn_softmax_kernel<<<NROWS / 4, 256, 0, stream>>>(dist, w_idx, w_val);

    const int nblocks = NROWS / 16;   // 2000
    const int WL = 16384;             // bf16 elements per layer in WB
    layer_kernel<<<nblocks, 256, 0, stream>>>(node_emb, w_idx, w_val,
        WB,          bs,           gammas,           betas,           out);
    layer_kernel<<<nblocks, 256, 0, stream>>>(out,      w_idx, w_val,
        WB + WL,     bs + HDIM,    gammas + HDIM,    betas + HDIM,    h_mid);
    layer_kernel<<<nblocks, 256, 0, stream>>>(h_mid,    w_idx, w_val,
        WB + 2*WL,   bs + 2*HDIM,  gammas + 2*HDIM,  betas + 2*HDIM,  out);
}